// Round 6
// baseline (197.574 us; speedup 1.0000x reference)
//
#include <hip/hip_runtime.h>
#include <hip/hip_bf16.h>

// Problem constants (from reference): B=8, T=4096, E=16, H=64
#define BB 8
#define TT 4096
#define EE 16
#define HH 64

typedef __attribute__((ext_vector_type(8))) __bf16 bf16x8;  // MFMA A/B frag (4 VGPRs)
typedef __attribute__((ext_vector_type(4))) float f32x4;    // MFMA C/D frag

typedef __attribute__((address_space(3))) void lds_void;
typedef const __attribute__((address_space(1))) void gl_void;

// e^(d^(-1/16)) ≈ P4(log2(d) - 5.5): degree-4 Taylor of exp(2^(-u/16)) about
// u=5.5. |rel err| < 2.5e-4 for d ∈ [2,1024] (hand-verified at d=8..1024),
// well inside bf16 noise. 1 transcendental + 5 VALU vs 3 transcendentals.
static __device__ __forceinline__ float exp_pow16(float d) {
    float t = __builtin_amdgcn_logf(d) - 5.5f;     // v_log_f32 = log2
    float r = __builtin_fmaf(t, 2.72889e-6f, -9.35716e-5f);
    r = __builtin_fmaf(t, r, 2.90736e-3f);
    r = __builtin_fmaf(t, r, -7.50656e-2f);
    r = __builtin_fmaf(t, r, 2.198967f);
    return r;
}

// ---- kernel 1: Qb = bf16(x@Wq), Kb = bf16(x@Wk) ----------------------------
__global__ __launch_bounds__(256) void proj_kernel(
        const float* __restrict__ x, const float* __restrict__ Wq,
        const float* __restrict__ Wk,
        __bf16* __restrict__ Qb, __bf16* __restrict__ Kb) {
    int tid = threadIdx.x;
    int row = blockIdx.x * 4 + (tid >> 6);
    int h = tid & 63;
    const float* xr = x + (size_t)row * EE;
    float q = 0.f, k = 0.f;
#pragma unroll
    for (int e = 0; e < EE; ++e) {
        float xv = xr[e];
        q += xv * Wq[e * HH + h];
        k += xv * Wk[e * HH + h];
    }
    size_t idx = (size_t)row * HH + h;
    Qb[idx] = (__bf16)q;
    Kb[idx] = (__bf16)k;
}

// ---- kernel 2 (fused): D[s]=sum_t exp(S) over FULL T, then VsT=Kb/D --------
// Block owns 32 s (2 s-tiles/wave, B-frags persistent); 4 waves split T 4-way.
// Atomic-free: per-wave colsum partials -> LDS -> block reduce -> fused vscale
// transpose-write of VsT. C/D layout (m89): col=lane&15 (=s), row=quad*4+reg.
__global__ __launch_bounds__(256, 4) void colsum_mfma(
        const __bf16* __restrict__ Qb, const __bf16* __restrict__ Kb,
        __bf16* __restrict__ VsT) {
    __shared__ float Dp[4][32];
    __shared__ float Dfull[32];
    __shared__ float tile[32][65];   // [s_local][h] for transpose write

    int lane = threadIdx.x & 63;
    int w = threadIdx.x >> 6;
    int quad = lane >> 4;
    int l15 = lane & 15;
    int b = blockIdx.y;
    int s0 = blockIdx.x * 32;

    const __bf16* Qbb = Qb + (size_t)b * TT * HH;
    const __bf16* Kbb = Kb + (size_t)b * TT * HH;

    bf16x8 bk[2][2];
#pragma unroll
    for (int st = 0; st < 2; ++st) {
        const __bf16* krow = Kbb + (size_t)(s0 + st * 16 + l15) * HH + quad * 8;
        bk[st][0] = *(const bf16x8*)(krow);
        bk[st][1] = *(const bf16x8*)(krow + 32);
    }

    const int TL = TT / 4;                    // 1024 t per wave
    int t0 = w * TL;
    float csum[2] = {0.f, 0.f};
    for (int tt = 0; tt < TL; tt += 32) {
        const __bf16* qrow0 = Qbb + (size_t)(t0 + tt + l15) * HH + quad * 8;
        bf16x8 a00 = *(const bf16x8*)(qrow0);
        bf16x8 a01 = *(const bf16x8*)(qrow0 + 32);
        bf16x8 a10 = *(const bf16x8*)(qrow0 + 16 * HH);
        bf16x8 a11 = *(const bf16x8*)(qrow0 + 16 * HH + 32);
#pragma unroll
        for (int st = 0; st < 2; ++st) {
            f32x4 c0 = {0.f, 0.f, 0.f, 0.f};
            f32x4 c1 = {0.f, 0.f, 0.f, 0.f};
            c0 = __builtin_amdgcn_mfma_f32_16x16x32_bf16(a00, bk[st][0], c0, 0, 0, 0);
            c1 = __builtin_amdgcn_mfma_f32_16x16x32_bf16(a10, bk[st][0], c1, 0, 0, 0);
            c0 = __builtin_amdgcn_mfma_f32_16x16x32_bf16(a01, bk[st][1], c0, 0, 0, 0);
            c1 = __builtin_amdgcn_mfma_f32_16x16x32_bf16(a11, bk[st][1], c1, 0, 0, 0);
            csum[st] += exp_pow16(c0[0]) + exp_pow16(c0[1])
                      + exp_pow16(c0[2]) + exp_pow16(c0[3])
                      + exp_pow16(c1[0]) + exp_pow16(c1[1])
                      + exp_pow16(c1[2]) + exp_pow16(c1[3]);
        }
    }
#pragma unroll
    for (int st = 0; st < 2; ++st) {
        float r = csum[st];
        r += __shfl_xor(r, 16, 64);           // sum across quads (t-rows)
        r += __shfl_xor(r, 32, 64);
        if (quad == 0) Dp[w][st * 16 + l15] = r;
    }
    __syncthreads();
    if (threadIdx.x < 32)
        Dfull[threadIdx.x] = Dp[0][threadIdx.x] + Dp[1][threadIdx.x]
                           + Dp[2][threadIdx.x] + Dp[3][threadIdx.x];
    __syncthreads();

    // Fused vscale: VsT[b][h][s0+c] = bf16(Kb[b][s0+c][h] / D[s0+c])
    {
        const __bf16* Kbase = Kbb + (size_t)s0 * HH;
        int sl = threadIdx.x >> 6;            // 0..3
        int h = threadIdx.x & 63;
#pragma unroll
        for (int it = 0; it < 8; ++it) {
            int s_local = sl + 4 * it;
            tile[s_local][h] = (float)Kbase[(size_t)s_local * HH + h] / Dfull[s_local];
        }
        __syncthreads();
        __bf16* Vb = VsT + (size_t)b * HH * TT;
        int c = threadIdx.x & 31;
        int h0 = threadIdx.x >> 5;            // 0..7
#pragma unroll
        for (int it = 0; it < 8; ++it) {
            int hh = h0 + 8 * it;
            Vb[(size_t)hh * TT + s0 + c] = (__bf16)tile[c][hh];
        }
    }
}

// ---- kernel 3: OP[z][b][t][h] = sum_{s in slice z} exp(S_ts) * VsT[h][s] ---
// Double-buffered block staging (R5 structure): stage chunk i+1, wait vmcnt(2)
// (chunk-i loads issued a full iteration ago), raw s_barrier — no vmcnt(0)
// drain. E transpose via per-wave LDS round-trip (C-layout -> A-layout).
__global__ __launch_bounds__(256, 4) void out_mfma(
        const __bf16* __restrict__ Qb, const __bf16* __restrict__ Kb,
        const __bf16* __restrict__ VsT, float* __restrict__ OP) {
    __shared__ __bf16 QKf[2][4][64][8];     // [buf][region sub*2+kh][lane][8]
    __shared__ __bf16 PVf[2][4][64][8];     // [buf][region ht][lane][8]
    __shared__ __bf16 Etile[4][2][16 * 40]; // per-wave, per-tile E transpose

    int lane = threadIdx.x & 63;
    int w = threadIdx.x >> 6;
    int quad = lane >> 4;
    int l15 = lane & 15;
    int b = blockIdx.y;
    int z = blockIdx.z;
    int t0 = blockIdx.x * 128 + w * 32;

    const __bf16* Qbb = Qb + (size_t)b * TT * HH;
    const __bf16* Kbb = Kb + (size_t)b * TT * HH;
    const __bf16* Vbb = VsT + (size_t)b * HH * TT;

    bf16x8 aq[2][2];
#pragma unroll
    for (int tile = 0; tile < 2; ++tile) {
        const __bf16* qrow = Qbb + (size_t)(t0 + tile * 16 + l15) * HH + quad * 8;
        aq[tile][0] = *(const bf16x8*)(qrow);
        aq[tile][1] = *(const bf16x8*)(qrow + 32);
    }

    f32x4 acc[2][4];
#pragma unroll
    for (int tile = 0; tile < 2; ++tile)
#pragma unroll
        for (int ht = 0; ht < 4; ++ht)
            acc[tile][ht] = (f32x4){0.f, 0.f, 0.f, 0.f};

    // Wave stages QK region w (sub=w>>1, kh=w&1) and PV region w (ht=w).
    const __bf16* gA = Kbb + (size_t)((w >> 1) * 16 + l15) * HH + quad * 8 + (w & 1) * 32;
    const __bf16* gB = Vbb + (size_t)(w * 16 + l15) * TT + quad * 8;

    const int SL = TT / gridDim.z;
    int s0z = z * SL, send = s0z + SL;

    __builtin_amdgcn_global_load_lds((gl_void*)(gA + (size_t)s0z * HH),
                                     (lds_void*)&QKf[0][w][0][0], 16, 0, 0);
    __builtin_amdgcn_global_load_lds((gl_void*)(gB + s0z),
                                     (lds_void*)&PVf[0][w][0][0], 16, 0, 0);

    int buf = 0;
    for (int s = s0z; s < send; s += 32) {
        int snext = (s + 32 < send) ? (s + 32) : s0z;   // last iter: dummy reload
        int nb = buf ^ 1;
        __builtin_amdgcn_global_load_lds((gl_void*)(gA + (size_t)snext * HH),
                                         (lds_void*)&QKf[nb][w][0][0], 16, 0, 0);
        __builtin_amdgcn_global_load_lds((gl_void*)(gB + snext),
                                         (lds_void*)&PVf[nb][w][0][0], 16, 0, 0);
        __builtin_amdgcn_s_waitcnt(0x0f72);   // vmcnt(2): all but newest 2 done
        __builtin_amdgcn_s_barrier();         // buf's regions visible to all waves

        bf16x8 bk[2][2], bv[4];
#pragma unroll
        for (int sub = 0; sub < 2; ++sub)
#pragma unroll
            for (int kh = 0; kh < 2; ++kh)
                bk[sub][kh] = *(const bf16x8*)&QKf[buf][sub * 2 + kh][lane][0];
#pragma unroll
        for (int ht = 0; ht < 4; ++ht)
            bv[ht] = *(const bf16x8*)&PVf[buf][ht][lane][0];

#pragma unroll
        for (int tile = 0; tile < 2; ++tile) {
#pragma unroll
            for (int sub = 0; sub < 2; ++sub) {
                f32x4 c = {0.f, 0.f, 0.f, 0.f};
                c = __builtin_amdgcn_mfma_f32_16x16x32_bf16(aq[tile][0], bk[sub][0], c, 0, 0, 0);
                c = __builtin_amdgcn_mfma_f32_16x16x32_bf16(aq[tile][1], bk[sub][1], c, 0, 0, 0);
                // C layout: row t_local = quad*4+r, col s_local = sub*16+l15
#pragma unroll
                for (int r = 0; r < 4; ++r)
                    Etile[w][tile][(quad * 4 + r) * 40 + sub * 16 + l15] =
                        (__bf16)exp_pow16(c[r]);
            }
        }
        __builtin_amdgcn_s_waitcnt(0xc07f);   // lgkmcnt(0): wave's E writes visible
#pragma unroll
        for (int tile = 0; tile < 2; ++tile) {
            bf16x8 aE = *(const bf16x8*)&Etile[w][tile][l15 * 40 + quad * 8];
#pragma unroll
            for (int ht = 0; ht < 4; ++ht)
                acc[tile][ht] = __builtin_amdgcn_mfma_f32_16x16x32_bf16(aE, bv[ht], acc[tile][ht], 0, 0, 0);
        }
        __builtin_amdgcn_s_waitcnt(0xc07f);   // all my LDS reads complete
        __builtin_amdgcn_s_barrier();         // buf now safe to overwrite
        buf = nb;
    }

    float* op = OP + (((size_t)z * BB + b) * TT + t0) * HH;
#pragma unroll
    for (int tile = 0; tile < 2; ++tile) {
#pragma unroll
        for (int r = 0; r < 4; ++r) {
            size_t ro = (size_t)(tile * 16 + quad * 4 + r) * HH + l15;
            op[ro]      = acc[tile][0][r];
            op[ro + 16] = acc[tile][1][r];
            op[ro + 32] = acc[tile][2][r];
            op[ro + 48] = acc[tile][3][r];
        }
    }
}

// ---- kernel 4: out = sum_z OP[z] -------------------------------------------
__global__ __launch_bounds__(256) void reduce_kernel(
        const float* __restrict__ OP, float* __restrict__ out, int nslice) {
    size_t i = (size_t)blockIdx.x * 256 + threadIdx.x;   // float4 units
    const size_t N4 = (size_t)BB * TT * HH / 4;
    if (i >= N4) return;
    const float4* p = (const float4*)OP;
    float4 a = p[i];
    for (int zz = 1; zz < nslice; ++zz) {
        float4 v = p[(size_t)zz * N4 + i];
        a.x += v.x; a.y += v.y; a.z += v.z; a.w += v.w;
    }
    ((float4*)out)[i] = a;
}

extern "C" void kernel_launch(void* const* d_in, const int* in_sizes, int n_in,
                              void* d_out, int out_size, void* d_ws, size_t ws_size,
                              hipStream_t stream) {
    const float* x  = (const float*)d_in[0];
    const float* Wq = (const float*)d_in[1];
    const float* Wk = (const float*)d_in[2];
    // d_in[3] (Wv) unused: reference computes v = x @ Wk (faithful quirk).

    const size_t NE = (size_t)BB * TT * HH;     // 2,097,152
    size_t base = NE * 2 * 3;
    int nslice = 4;
    if (base + (size_t)4 * NE * 4 > ws_size) nslice = 2;

    char* wp = (char*)d_ws;
    __bf16* Qb  = (__bf16*)wp;  wp += NE * 2;
    __bf16* Kb  = (__bf16*)wp;  wp += NE * 2;
    __bf16* VsT = (__bf16*)wp;  wp += NE * 2;
    float*  OP  = (float*)wp;
    float* out = (float*)d_out;

    proj_kernel<<<BB * TT / 4, 256, 0, stream>>>(x, Wq, Wk, Qb, Kb);
    colsum_mfma<<<dim3(TT / 32, BB), 256, 0, stream>>>(Qb, Kb, VsT);
    out_mfma<<<dim3(TT / 128, BB, nslice), 256, 0, stream>>>(Qb, Kb, VsT, OP);
    reduce_kernel<<<(int)((NE / 4 + 255) / 256), 256, 0, stream>>>(OP, out, nslice);
}

// Round 7
// 175.030 us; speedup vs baseline: 1.1288x; 1.1288x over previous
//
#include <hip/hip_runtime.h>
#include <hip/hip_bf16.h>

// Problem constants (from reference): B=8, T=4096, E=16, H=64
#define BB 8
#define TT 4096
#define EE 16
#define HH 64
#define ZT 4       // colsum t-chunk split (atomic-free partials)

typedef __attribute__((ext_vector_type(8))) __bf16 bf16x8;  // MFMA A/B frag (4 VGPRs)
typedef __attribute__((ext_vector_type(4))) float f32x4;    // MFMA C/D frag

typedef __attribute__((address_space(3))) void lds_void;
typedef const __attribute__((address_space(1))) void gl_void;

// e^(d^(-1/16)) ≈ P4(log2(d) - 5.5): degree-4 Taylor of exp(2^(-u/16)) about
// u=5.5. |rel err| < 2.5e-4 for d ∈ [2,1024] — inside bf16 noise (validated
// R6: absmax identical to 3-transcendental version). 1 transc + 5 VALU.
static __device__ __forceinline__ float exp_pow16(float d) {
    float t = __builtin_amdgcn_logf(d) - 5.5f;     // v_log_f32 = log2
    float r = __builtin_fmaf(t, 2.72889e-6f, -9.35716e-5f);
    r = __builtin_fmaf(t, r, 2.90736e-3f);
    r = __builtin_fmaf(t, r, -7.50656e-2f);
    r = __builtin_fmaf(t, r, 2.198967f);
    return r;
}

// ---- kernel 1: Qb = bf16(x@Wq), Kb = bf16(x@Wk) ----------------------------
__global__ __launch_bounds__(256) void proj_kernel(
        const float* __restrict__ x, const float* __restrict__ Wq,
        const float* __restrict__ Wk,
        __bf16* __restrict__ Qb, __bf16* __restrict__ Kb) {
    int tid = threadIdx.x;
    int row = blockIdx.x * 4 + (tid >> 6);
    int h = tid & 63;
    const float* xr = x + (size_t)row * EE;
    float q = 0.f, k = 0.f;
#pragma unroll
    for (int e = 0; e < EE; ++e) {
        float xv = xr[e];
        q += xv * Wq[e * HH + h];
        k += xv * Wk[e * HH + h];
    }
    size_t idx = (size_t)row * HH + h;
    Qb[idx] = (__bf16)q;
    Kb[idx] = (__bf16)k;
}

// ---- kernel 2: Dpart[z][b][s] = sum_{t in chunk z} exp((q_t.k_s)^(-1/16)) --
// Staged-Q mirror of out_mfma's pipeline: block owns 256 s (wave w owns 64 s =
// 4 persistent B-frag tiles); all 4 waves consume the SAME staged Q A-frags
// (32 t/iter, 4 regions x 1KB, wave w stages region w via global_load_lds,
// dbuf + vmcnt(1) + raw s_barrier). Atomic-free: partials per t-chunk.
// C/D layout (m89): col = lane&15 (=s), row = quad*4+reg (=t).
__global__ __launch_bounds__(256, 4) void colsum_mfma(
        const __bf16* __restrict__ Qb, const __bf16* __restrict__ Kb,
        float* __restrict__ Dpart) {
    __shared__ __bf16 QKf[2][4][64][8];   // [buf][region tsub*2+kh][lane][8]

    int lane = threadIdx.x & 63;
    int w = threadIdx.x >> 6;
    int quad = lane >> 4;
    int l15 = lane & 15;
    int b = blockIdx.y;
    int z = blockIdx.z;
    int s0 = blockIdx.x * 256 + w * 64;

    const __bf16* Qbb = Qb + (size_t)b * TT * HH;
    const __bf16* Kbb = Kb + (size_t)b * TT * HH;

    // Persistent B-frags: 4 s-tiles (64 s per wave)
    bf16x8 bk[4][2];
#pragma unroll
    for (int st = 0; st < 4; ++st) {
        const __bf16* krow = Kbb + (size_t)(s0 + st * 16 + l15) * HH + quad * 8;
        bk[st][0] = *(const bf16x8*)(krow);
        bk[st][1] = *(const bf16x8*)(krow + 32);
    }

    // Wave stages A-frag region w: tsub = w>>1, kh = w&1.
    const __bf16* gA = Qbb + (size_t)((w >> 1) * 16 + l15) * HH + quad * 8 + (w & 1) * 32;

    const int TL = TT / ZT;                  // 1024 t per block
    int t0 = z * TL, tend = t0 + TL;

    __builtin_amdgcn_global_load_lds((gl_void*)(gA + (size_t)t0 * HH),
                                     (lds_void*)&QKf[0][w][0][0], 16, 0, 0);

    float csum[4] = {0.f, 0.f, 0.f, 0.f};
    int buf = 0;
    for (int t = t0; t < tend; t += 32) {
        int tn = (t + 32 < tend) ? (t + 32) : t0;   // last iter: dummy reload
        int nb = buf ^ 1;
        __builtin_amdgcn_global_load_lds((gl_void*)(gA + (size_t)tn * HH),
                                         (lds_void*)&QKf[nb][w][0][0], 16, 0, 0);
        __builtin_amdgcn_s_waitcnt(0x0f71);   // vmcnt(1): chunk-t stage complete
        __builtin_amdgcn_s_barrier();

        bf16x8 aq[2][2];
#pragma unroll
        for (int tsub = 0; tsub < 2; ++tsub)
#pragma unroll
            for (int kh = 0; kh < 2; ++kh)
                aq[tsub][kh] = *(const bf16x8*)&QKf[buf][tsub * 2 + kh][lane][0];

#pragma unroll
        for (int st = 0; st < 4; ++st) {
            f32x4 c0 = {0.f, 0.f, 0.f, 0.f};
            f32x4 c1 = {0.f, 0.f, 0.f, 0.f};
            c0 = __builtin_amdgcn_mfma_f32_16x16x32_bf16(aq[0][0], bk[st][0], c0, 0, 0, 0);
            c1 = __builtin_amdgcn_mfma_f32_16x16x32_bf16(aq[1][0], bk[st][0], c1, 0, 0, 0);
            c0 = __builtin_amdgcn_mfma_f32_16x16x32_bf16(aq[0][1], bk[st][1], c0, 0, 0, 0);
            c1 = __builtin_amdgcn_mfma_f32_16x16x32_bf16(aq[1][1], bk[st][1], c1, 0, 0, 0);
            csum[st] += exp_pow16(c0[0]) + exp_pow16(c0[1])
                      + exp_pow16(c0[2]) + exp_pow16(c0[3])
                      + exp_pow16(c1[0]) + exp_pow16(c1[1])
                      + exp_pow16(c1[2]) + exp_pow16(c1[3]);
        }
        __builtin_amdgcn_s_waitcnt(0xc07f);   // lgkmcnt(0): my LDS reads done
        __builtin_amdgcn_s_barrier();         // buf safe to overwrite
        buf = nb;
    }

#pragma unroll
    for (int st = 0; st < 4; ++st) {
        float r = csum[st];
        r += __shfl_xor(r, 16, 64);           // sum across quads (t-rows)
        r += __shfl_xor(r, 32, 64);
        if (quad == 0)
            Dpart[((size_t)z * BB + b) * TT + s0 + st * 16 + l15] = r;
    }
}

// ---- kernel 3: VsT[b][h][s] = bf16(Kb[b][s][h]) / sum_z Dpart[z][b][s] -----
__global__ __launch_bounds__(256) void vscale_kernel(
        const __bf16* __restrict__ Kb, const float* __restrict__ Dpart,
        __bf16* __restrict__ VsT) {
    __shared__ float tile[64][65];
    __shared__ float Rs[64];                  // 1/D per s_local
    int b = blockIdx.y;
    int s0 = blockIdx.x * 64;
    int c = threadIdx.x & 63;
    int rr = threadIdx.x >> 6;
    if (threadIdx.x < 64) {
        size_t si = (size_t)b * TT + s0 + threadIdx.x;
        float d = Dpart[si];
#pragma unroll
        for (int zz = 1; zz < ZT; ++zz) d += Dpart[(size_t)zz * BB * TT + si];
        Rs[threadIdx.x] = 1.0f / d;
    }
    __syncthreads();
    const __bf16* Kbase = Kb + ((size_t)b * TT + s0) * HH;
#pragma unroll
    for (int i = rr; i < 64; i += 4)
        tile[i][c] = (float)Kbase[(size_t)i * HH + c] * Rs[i];   // tile[s_local][h]
    __syncthreads();
    __bf16* Vb = VsT + (size_t)b * HH * TT;
#pragma unroll
    for (int i = rr; i < 64; i += 4)
        Vb[(size_t)i * TT + s0 + c] = (__bf16)tile[c][i];        // VsT[h=i][s=s0+c]
}

// ---- kernel 4: OP[z][b][t][h] = sum_{s in slice z} exp(S_ts) * VsT[h][s] ---
// R5/R6 structure: dbuf block staging, vmcnt(2), raw barriers, per-wave LDS
// E-transpose (C-layout -> A-layout), poly exp.
__global__ __launch_bounds__(256, 4) void out_mfma(
        const __bf16* __restrict__ Qb, const __bf16* __restrict__ Kb,
        const __bf16* __restrict__ VsT, float* __restrict__ OP) {
    __shared__ __bf16 QKf[2][4][64][8];     // [buf][region sub*2+kh][lane][8]
    __shared__ __bf16 PVf[2][4][64][8];     // [buf][region ht][lane][8]
    __shared__ __bf16 Etile[4][2][16 * 40]; // per-wave, per-tile E transpose

    int lane = threadIdx.x & 63;
    int w = threadIdx.x >> 6;
    int quad = lane >> 4;
    int l15 = lane & 15;
    int b = blockIdx.y;
    int z = blockIdx.z;
    int t0 = blockIdx.x * 128 + w * 32;

    const __bf16* Qbb = Qb + (size_t)b * TT * HH;
    const __bf16* Kbb = Kb + (size_t)b * TT * HH;
    const __bf16* Vbb = VsT + (size_t)b * HH * TT;

    bf16x8 aq[2][2];
#pragma unroll
    for (int tile = 0; tile < 2; ++tile) {
        const __bf16* qrow = Qbb + (size_t)(t0 + tile * 16 + l15) * HH + quad * 8;
        aq[tile][0] = *(const bf16x8*)(qrow);
        aq[tile][1] = *(const bf16x8*)(qrow + 32);
    }

    f32x4 acc[2][4];
#pragma unroll
    for (int tile = 0; tile < 2; ++tile)
#pragma unroll
        for (int ht = 0; ht < 4; ++ht)
            acc[tile][ht] = (f32x4){0.f, 0.f, 0.f, 0.f};

    const __bf16* gA = Kbb + (size_t)((w >> 1) * 16 + l15) * HH + quad * 8 + (w & 1) * 32;
    const __bf16* gB = Vbb + (size_t)(w * 16 + l15) * TT + quad * 8;

    const int SL = TT / gridDim.z;
    int s0z = z * SL, send = s0z + SL;

    __builtin_amdgcn_global_load_lds((gl_void*)(gA + (size_t)s0z * HH),
                                     (lds_void*)&QKf[0][w][0][0], 16, 0, 0);
    __builtin_amdgcn_global_load_lds((gl_void*)(gB + s0z),
                                     (lds_void*)&PVf[0][w][0][0], 16, 0, 0);

    int buf = 0;
    for (int s = s0z; s < send; s += 32) {
        int snext = (s + 32 < send) ? (s + 32) : s0z;   // last iter: dummy reload
        int nb = buf ^ 1;
        __builtin_amdgcn_global_load_lds((gl_void*)(gA + (size_t)snext * HH),
                                         (lds_void*)&QKf[nb][w][0][0], 16, 0, 0);
        __builtin_amdgcn_global_load_lds((gl_void*)(gB + snext),
                                         (lds_void*)&PVf[nb][w][0][0], 16, 0, 0);
        __builtin_amdgcn_s_waitcnt(0x0f72);   // vmcnt(2): all but newest 2 done
        __builtin_amdgcn_s_barrier();

        bf16x8 bk[2][2], bv[4];
#pragma unroll
        for (int sub = 0; sub < 2; ++sub)
#pragma unroll
            for (int kh = 0; kh < 2; ++kh)
                bk[sub][kh] = *(const bf16x8*)&QKf[buf][sub * 2 + kh][lane][0];
#pragma unroll
        for (int ht = 0; ht < 4; ++ht)
            bv[ht] = *(const bf16x8*)&PVf[buf][ht][lane][0];

#pragma unroll
        for (int tile = 0; tile < 2; ++tile) {
#pragma unroll
            for (int sub = 0; sub < 2; ++sub) {
                f32x4 c = {0.f, 0.f, 0.f, 0.f};
                c = __builtin_amdgcn_mfma_f32_16x16x32_bf16(aq[tile][0], bk[sub][0], c, 0, 0, 0);
                c = __builtin_amdgcn_mfma_f32_16x16x32_bf16(aq[tile][1], bk[sub][1], c, 0, 0, 0);
#pragma unroll
                for (int r = 0; r < 4; ++r)
                    Etile[w][tile][(quad * 4 + r) * 40 + sub * 16 + l15] =
                        (__bf16)exp_pow16(c[r]);
            }
        }
        __builtin_amdgcn_s_waitcnt(0xc07f);   // lgkmcnt(0): E writes visible
#pragma unroll
        for (int tile = 0; tile < 2; ++tile) {
            bf16x8 aE = *(const bf16x8*)&Etile[w][tile][l15 * 40 + quad * 8];
#pragma unroll
            for (int ht = 0; ht < 4; ++ht)
                acc[tile][ht] = __builtin_amdgcn_mfma_f32_16x16x32_bf16(aE, bv[ht], acc[tile][ht], 0, 0, 0);
        }
        __builtin_amdgcn_s_waitcnt(0xc07f);   // my LDS reads complete
        __builtin_amdgcn_s_barrier();         // buf safe to overwrite
        buf = nb;
    }

    float* op = OP + (((size_t)z * BB + b) * TT + t0) * HH;
#pragma unroll
    for (int tile = 0; tile < 2; ++tile) {
#pragma unroll
        for (int r = 0; r < 4; ++r) {
            size_t ro = (size_t)(tile * 16 + quad * 4 + r) * HH + l15;
            op[ro]      = acc[tile][0][r];
            op[ro + 16] = acc[tile][1][r];
            op[ro + 32] = acc[tile][2][r];
            op[ro + 48] = acc[tile][3][r];
        }
    }
}

// ---- kernel 5: out = sum_z OP[z] -------------------------------------------
__global__ __launch_bounds__(256) void reduce_kernel(
        const float* __restrict__ OP, float* __restrict__ out, int nslice) {
    size_t i = (size_t)blockIdx.x * 256 + threadIdx.x;   // float4 units
    const size_t N4 = (size_t)BB * TT * HH / 4;
    if (i >= N4) return;
    const float4* p = (const float4*)OP;
    float4 a = p[i];
    for (int zz = 1; zz < nslice; ++zz) {
        float4 v = p[(size_t)zz * N4 + i];
        a.x += v.x; a.y += v.y; a.z += v.z; a.w += v.w;
    }
    ((float4*)out)[i] = a;
}

extern "C" void kernel_launch(void* const* d_in, const int* in_sizes, int n_in,
                              void* d_out, int out_size, void* d_ws, size_t ws_size,
                              hipStream_t stream) {
    const float* x  = (const float*)d_in[0];
    const float* Wq = (const float*)d_in[1];
    const float* Wk = (const float*)d_in[2];
    // d_in[3] (Wv) unused: reference computes v = x @ Wk (faithful quirk).

    const size_t NE = (size_t)BB * TT * HH;     // 2,097,152
    size_t base = NE * 2 * 3 + (size_t)ZT * BB * TT * 4;
    int nslice = 4;
    if (base + (size_t)4 * NE * 4 > ws_size) nslice = 2;

    char* wp = (char*)d_ws;
    __bf16* Qb    = (__bf16*)wp;  wp += NE * 2;
    __bf16* Kb    = (__bf16*)wp;  wp += NE * 2;
    __bf16* VsT   = (__bf16*)wp;  wp += NE * 2;
    float*  Dpart = (float*)wp;   wp += (size_t)ZT * BB * TT * 4;
    float*  OP    = (float*)wp;
    float* out = (float*)d_out;

    proj_kernel<<<BB * TT / 4, 256, 0, stream>>>(x, Wq, Wk, Qb, Kb);
    colsum_mfma<<<dim3(TT / 256, BB, ZT), 256, 0, stream>>>(Qb, Kb, Dpart);
    vscale_kernel<<<dim3(TT / 64, BB), 256, 0, stream>>>(Kb, Dpart, VsT);
    out_mfma<<<dim3(TT / 128, BB, nslice), 256, 0, stream>>>(Qb, Kb, VsT, OP);
    reduce_kernel<<<(int)((NE / 4 + 255) / 256), 256, 0, stream>>>(OP, out, nslice);
}

// Round 8
// 169.084 us; speedup vs baseline: 1.1685x; 1.0352x over previous
//
#include <hip/hip_runtime.h>
#include <hip/hip_bf16.h>

// Problem constants (from reference): B=8, T=4096, E=16, H=64
#define BB 8
#define TT 4096
#define EE 16
#define HH 64
#define ZT 4       // colsum t-chunk split (atomic-free partials)

typedef __attribute__((ext_vector_type(8))) __bf16 bf16x8;  // MFMA A/B frag (4 VGPRs)
typedef __attribute__((ext_vector_type(4))) __bf16 bf16x4;  // packed E write (8B)
typedef __attribute__((ext_vector_type(4))) float f32x4;    // MFMA C/D frag

typedef __attribute__((address_space(3))) void lds_void;
typedef const __attribute__((address_space(1))) void gl_void;

// e^(d^(-1/16)) ≈ P4(log2(d) - 5.5): degree-4 Taylor of exp(2^(-u/16)) about
// u=5.5. |rel err| < 2.5e-4 for d ∈ [2,1024] — inside bf16 noise (validated
// R6/R7: absmax identical to 3-transcendental version). 1 transc + 5 VALU.
static __device__ __forceinline__ float exp_pow16(float d) {
    float t = __builtin_amdgcn_logf(d) - 5.5f;     // v_log_f32 = log2
    float r = __builtin_fmaf(t, 2.72889e-6f, -9.35716e-5f);
    r = __builtin_fmaf(t, r, 2.90736e-3f);
    r = __builtin_fmaf(t, r, -7.50656e-2f);
    r = __builtin_fmaf(t, r, 2.198967f);
    return r;
}

// ---- kernel 1: Qb = bf16(x@Wq), Kb = bf16(x@Wk) ----------------------------
__global__ __launch_bounds__(256) void proj_kernel(
        const float* __restrict__ x, const float* __restrict__ Wq,
        const float* __restrict__ Wk,
        __bf16* __restrict__ Qb, __bf16* __restrict__ Kb) {
    int tid = threadIdx.x;
    int row = blockIdx.x * 4 + (tid >> 6);
    int h = tid & 63;
    const float* xr = x + (size_t)row * EE;
    float q = 0.f, k = 0.f;
#pragma unroll
    for (int e = 0; e < EE; ++e) {
        float xv = xr[e];
        q += xv * Wq[e * HH + h];
        k += xv * Wk[e * HH + h];
    }
    size_t idx = (size_t)row * HH + h;
    Qb[idx] = (__bf16)q;
    Kb[idx] = (__bf16)k;
}

// ---- kernel 2: Dpart[z][b][s] = sum_{t in chunk z} exp((q_t.k_s)^(-1/16)) --
// R7 structure (verified win): block owns 256 s (wave w owns 64 s = 4
// persistent B-frag tiles); all 4 waves consume the SAME staged Q A-frags
// (32 t/iter, wave w stages region w, dbuf + vmcnt(1) + raw s_barrier).
__global__ __launch_bounds__(256, 4) void colsum_mfma(
        const __bf16* __restrict__ Qb, const __bf16* __restrict__ Kb,
        float* __restrict__ Dpart) {
    __shared__ __bf16 QKf[2][4][64][8];   // [buf][region tsub*2+kh][lane][8]

    int lane = threadIdx.x & 63;
    int w = threadIdx.x >> 6;
    int quad = lane >> 4;
    int l15 = lane & 15;
    int b = blockIdx.y;
    int z = blockIdx.z;
    int s0 = blockIdx.x * 256 + w * 64;

    const __bf16* Qbb = Qb + (size_t)b * TT * HH;
    const __bf16* Kbb = Kb + (size_t)b * TT * HH;

    bf16x8 bk[4][2];
#pragma unroll
    for (int st = 0; st < 4; ++st) {
        const __bf16* krow = Kbb + (size_t)(s0 + st * 16 + l15) * HH + quad * 8;
        bk[st][0] = *(const bf16x8*)(krow);
        bk[st][1] = *(const bf16x8*)(krow + 32);
    }

    const __bf16* gA = Qbb + (size_t)((w >> 1) * 16 + l15) * HH + quad * 8 + (w & 1) * 32;

    const int TL = TT / ZT;                  // 1024 t per block
    int t0 = z * TL, tend = t0 + TL;

    __builtin_amdgcn_global_load_lds((gl_void*)(gA + (size_t)t0 * HH),
                                     (lds_void*)&QKf[0][w][0][0], 16, 0, 0);

    float csum[4] = {0.f, 0.f, 0.f, 0.f};
    int buf = 0;
    for (int t = t0; t < tend; t += 32) {
        int tn = (t + 32 < tend) ? (t + 32) : t0;   // last iter: dummy reload
        int nb = buf ^ 1;
        __builtin_amdgcn_global_load_lds((gl_void*)(gA + (size_t)tn * HH),
                                         (lds_void*)&QKf[nb][w][0][0], 16, 0, 0);
        __builtin_amdgcn_s_waitcnt(0x0f71);   // vmcnt(1): chunk-t stage complete
        __builtin_amdgcn_s_barrier();

        bf16x8 aq[2][2];
#pragma unroll
        for (int tsub = 0; tsub < 2; ++tsub)
#pragma unroll
            for (int kh = 0; kh < 2; ++kh)
                aq[tsub][kh] = *(const bf16x8*)&QKf[buf][tsub * 2 + kh][lane][0];

#pragma unroll
        for (int st = 0; st < 4; ++st) {
            f32x4 c0 = {0.f, 0.f, 0.f, 0.f};
            f32x4 c1 = {0.f, 0.f, 0.f, 0.f};
            c0 = __builtin_amdgcn_mfma_f32_16x16x32_bf16(aq[0][0], bk[st][0], c0, 0, 0, 0);
            c1 = __builtin_amdgcn_mfma_f32_16x16x32_bf16(aq[1][0], bk[st][0], c1, 0, 0, 0);
            c0 = __builtin_amdgcn_mfma_f32_16x16x32_bf16(aq[0][1], bk[st][1], c0, 0, 0, 0);
            c1 = __builtin_amdgcn_mfma_f32_16x16x32_bf16(aq[1][1], bk[st][1], c1, 0, 0, 0);
            csum[st] += exp_pow16(c0[0]) + exp_pow16(c0[1])
                      + exp_pow16(c0[2]) + exp_pow16(c0[3])
                      + exp_pow16(c1[0]) + exp_pow16(c1[1])
                      + exp_pow16(c1[2]) + exp_pow16(c1[3]);
        }
        __builtin_amdgcn_s_waitcnt(0xc07f);   // lgkmcnt(0): my LDS reads done
        __builtin_amdgcn_s_barrier();         // buf safe to overwrite
        buf = nb;
    }

#pragma unroll
    for (int st = 0; st < 4; ++st) {
        float r = csum[st];
        r += __shfl_xor(r, 16, 64);           // sum across quads (t-rows)
        r += __shfl_xor(r, 32, 64);
        if (quad == 0)
            Dpart[((size_t)z * BB + b) * TT + s0 + st * 16 + l15] = r;
    }
}

// ---- kernel 3: VsT[b][h][s] = bf16(Kb[b][s][h]) / sum_z Dpart[z][b][s] -----
__global__ __launch_bounds__(256) void vscale_kernel(
        const __bf16* __restrict__ Kb, const float* __restrict__ Dpart,
        __bf16* __restrict__ VsT) {
    __shared__ float tile[64][65];
    __shared__ float Rs[64];                  // 1/D per s_local
    int b = blockIdx.y;
    int s0 = blockIdx.x * 64;
    int c = threadIdx.x & 63;
    int rr = threadIdx.x >> 6;
    if (threadIdx.x < 64) {
        size_t si = (size_t)b * TT + s0 + threadIdx.x;
        float d = Dpart[si];
#pragma unroll
        for (int zz = 1; zz < ZT; ++zz) d += Dpart[(size_t)zz * BB * TT + si];
        Rs[threadIdx.x] = 1.0f / d;
    }
    __syncthreads();
    const __bf16* Kbase = Kb + ((size_t)b * TT + s0) * HH;
#pragma unroll
    for (int i = rr; i < 64; i += 4)
        tile[i][c] = (float)Kbase[(size_t)i * HH + c] * Rs[i];   // tile[s_local][h]
    __syncthreads();
    __bf16* Vb = VsT + (size_t)b * HH * TT;
#pragma unroll
    for (int i = rr; i < 64; i += 4)
        Vb[(size_t)i * TT + s0 + c] = (__bf16)tile[c][i];        // VsT[h=i][s=s0+c]
}

// ---- kernel 4: OP[z][b][t][h] = sum_{s in slice z} exp(S_ts) * VsT[h][s] ---
// R8 change: QK MFMA computes S^T (operand swap A=K,B=Q — frag layouts are
// identical so zero data-movement cost). C rows are now s = quad*4+r: the 4
// regs are 4 CONSECUTIVE s for fixed t=l15, so the E[t][s] transpose write is
// one packed ds_write_b64 per (tile,sub) instead of 16 ds_write_b16.
__global__ __launch_bounds__(256, 4) void out_mfma(
        const __bf16* __restrict__ Qb, const __bf16* __restrict__ Kb,
        const __bf16* __restrict__ VsT, float* __restrict__ OP) {
    __shared__ __bf16 QKf[2][4][64][8];     // [buf][region sub*2+kh][lane][8]
    __shared__ __bf16 PVf[2][4][64][8];     // [buf][region ht][lane][8]
    __shared__ __bf16 Etile[4][2][16 * 40]; // per-wave, per-tile E[t 16][s 32+pad8]

    int lane = threadIdx.x & 63;
    int w = threadIdx.x >> 6;
    int quad = lane >> 4;
    int l15 = lane & 15;
    int b = blockIdx.y;
    int z = blockIdx.z;
    int t0 = blockIdx.x * 128 + w * 32;

    const __bf16* Qbb = Qb + (size_t)b * TT * HH;
    const __bf16* Kbb = Kb + (size_t)b * TT * HH;
    const __bf16* Vbb = VsT + (size_t)b * HH * TT;

    bf16x8 aq[2][2];
#pragma unroll
    for (int tile = 0; tile < 2; ++tile) {
        const __bf16* qrow = Qbb + (size_t)(t0 + tile * 16 + l15) * HH + quad * 8;
        aq[tile][0] = *(const bf16x8*)(qrow);
        aq[tile][1] = *(const bf16x8*)(qrow + 32);
    }

    f32x4 acc[2][4];
#pragma unroll
    for (int tile = 0; tile < 2; ++tile)
#pragma unroll
        for (int ht = 0; ht < 4; ++ht)
            acc[tile][ht] = (f32x4){0.f, 0.f, 0.f, 0.f};

    const __bf16* gA = Kbb + (size_t)((w >> 1) * 16 + l15) * HH + quad * 8 + (w & 1) * 32;
    const __bf16* gB = Vbb + (size_t)(w * 16 + l15) * TT + quad * 8;

    const int SL = TT / gridDim.z;
    int s0z = z * SL, send = s0z + SL;

    __builtin_amdgcn_global_load_lds((gl_void*)(gA + (size_t)s0z * HH),
                                     (lds_void*)&QKf[0][w][0][0], 16, 0, 0);
    __builtin_amdgcn_global_load_lds((gl_void*)(gB + s0z),
                                     (lds_void*)&PVf[0][w][0][0], 16, 0, 0);

    int buf = 0;
    for (int s = s0z; s < send; s += 32) {
        int snext = (s + 32 < send) ? (s + 32) : s0z;   // last iter: dummy reload
        int nb = buf ^ 1;
        __builtin_amdgcn_global_load_lds((gl_void*)(gA + (size_t)snext * HH),
                                         (lds_void*)&QKf[nb][w][0][0], 16, 0, 0);
        __builtin_amdgcn_global_load_lds((gl_void*)(gB + snext),
                                         (lds_void*)&PVf[nb][w][0][0], 16, 0, 0);
        __builtin_amdgcn_s_waitcnt(0x0f72);   // vmcnt(2): all but newest 2 done
        __builtin_amdgcn_s_barrier();

        bf16x8 bk[2][2], bv[4];
#pragma unroll
        for (int sub = 0; sub < 2; ++sub)
#pragma unroll
            for (int kh = 0; kh < 2; ++kh)
                bk[sub][kh] = *(const bf16x8*)&QKf[buf][sub * 2 + kh][lane][0];
#pragma unroll
        for (int ht = 0; ht < 4; ++ht)
            bv[ht] = *(const bf16x8*)&PVf[buf][ht][lane][0];

#pragma unroll
        for (int tile = 0; tile < 2; ++tile) {
#pragma unroll
            for (int sub = 0; sub < 2; ++sub) {
                // S^T: A=K (m=s), B=Q (n=t) -> row = s_local = quad*4+r,
                // col = t_local = l15. 4 regs = 4 consecutive s.
                f32x4 c = {0.f, 0.f, 0.f, 0.f};
                c = __builtin_amdgcn_mfma_f32_16x16x32_bf16(bk[sub][0], aq[tile][0], c, 0, 0, 0);
                c = __builtin_amdgcn_mfma_f32_16x16x32_bf16(bk[sub][1], aq[tile][1], c, 0, 0, 0);
                bf16x4 e;
#pragma unroll
                for (int r = 0; r < 4; ++r)
                    e[r] = (__bf16)exp_pow16(c[r]);
                // E[t=l15][s = sub*16 + quad*4 .. +3]: one packed 8B write
                *(bf16x4*)&Etile[w][tile][l15 * 40 + sub * 16 + quad * 4] = e;
            }
        }
        __builtin_amdgcn_s_waitcnt(0xc07f);   // lgkmcnt(0): E writes visible
#pragma unroll
        for (int tile = 0; tile < 2; ++tile) {
            // A-frag from E: A[m=t=l15][k=s=quad*8+j] — contiguous b128
            bf16x8 aE = *(const bf16x8*)&Etile[w][tile][l15 * 40 + quad * 8];
#pragma unroll
            for (int ht = 0; ht < 4; ++ht)
                acc[tile][ht] = __builtin_amdgcn_mfma_f32_16x16x32_bf16(aE, bv[ht], acc[tile][ht], 0, 0, 0);
        }
        __builtin_amdgcn_s_waitcnt(0xc07f);   // my LDS reads complete
        __builtin_amdgcn_s_barrier();         // buf safe to overwrite
        buf = nb;
    }

    float* op = OP + (((size_t)z * BB + b) * TT + t0) * HH;
#pragma unroll
    for (int tile = 0; tile < 2; ++tile) {
#pragma unroll
        for (int r = 0; r < 4; ++r) {
            size_t ro = (size_t)(tile * 16 + quad * 4 + r) * HH + l15;
            op[ro]      = acc[tile][0][r];
            op[ro + 16] = acc[tile][1][r];
            op[ro + 32] = acc[tile][2][r];
            op[ro + 48] = acc[tile][3][r];
        }
    }
}

// ---- kernel 5: out = sum_z OP[z] -------------------------------------------
__global__ __launch_bounds__(256) void reduce_kernel(
        const float* __restrict__ OP, float* __restrict__ out, int nslice) {
    size_t i = (size_t)blockIdx.x * 256 + threadIdx.x;   // float4 units
    const size_t N4 = (size_t)BB * TT * HH / 4;
    if (i >= N4) return;
    const float4* p = (const float4*)OP;
    float4 a = p[i];
    for (int zz = 1; zz < nslice; ++zz) {
        float4 v = p[(size_t)zz * N4 + i];
        a.x += v.x; a.y += v.y; a.z += v.z; a.w += v.w;
    }
    ((float4*)out)[i] = a;
}

extern "C" void kernel_launch(void* const* d_in, const int* in_sizes, int n_in,
                              void* d_out, int out_size, void* d_ws, size_t ws_size,
                              hipStream_t stream) {
    const float* x  = (const float*)d_in[0];
    const float* Wq = (const float*)d_in[1];
    const float* Wk = (const float*)d_in[2];
    // d_in[3] (Wv) unused: reference computes v = x @ Wk (faithful quirk).

    const size_t NE = (size_t)BB * TT * HH;     // 2,097,152
    size_t base = NE * 2 * 3 + (size_t)ZT * BB * TT * 4;
    int nslice = 4;
    if (base + (size_t)4 * NE * 4 > ws_size) nslice = 2;

    char* wp = (char*)d_ws;
    __bf16* Qb    = (__bf16*)wp;  wp += NE * 2;
    __bf16* Kb    = (__bf16*)wp;  wp += NE * 2;
    __bf16* VsT   = (__bf16*)wp;  wp += NE * 2;
    float*  Dpart = (float*)wp;   wp += (size_t)ZT * BB * TT * 4;
    float*  OP    = (float*)wp;
    float* out = (float*)d_out;

    proj_kernel<<<BB * TT / 4, 256, 0, stream>>>(x, Wq, Wk, Qb, Kb);
    colsum_mfma<<<dim3(TT / 256, BB, ZT), 256, 0, stream>>>(Qb, Kb, Dpart);
    vscale_kernel<<<dim3(TT / 64, BB), 256, 0, stream>>>(Kb, Dpart, VsT);
    out_mfma<<<dim3(TT / 128, BB, nslice), 256, 0, stream>>>(Qb, Kb, VsT, OP);
    reduce_kernel<<<(int)((NE / 4 + 255) / 256), 256, 0, stream>>>(OP, out, nslice);
}